// Round 5
// baseline (221.897 us; speedup 1.0000x reference)
//
#include <hip/hip_runtime.h>

typedef _Float16 f16;
typedef _Float16 f16x4 __attribute__((ext_vector_type(4)));
typedef _Float16 f16x8 __attribute__((ext_vector_type(8)));
typedef float f32x4 __attribute__((ext_vector_type(4)));

#define B_TOT 16384
#define HID_  512
#define LAT_  16
#define STY_  64
#define ND_   8

#define ROWS 32            // rows (samples) per block, carried in LDS through all layers
#define MAXBLK 520         // ceil((16384 + 8*31)/32)

// async global->LDS, 16B per lane; LDS dest must be wave-uniform base (+lane*16)
__device__ __forceinline__ void gload16(const f16* g, f16* l) {
  __builtin_amdgcn_global_load_lds(
      (const __attribute__((address_space(1))) unsigned int*)g,
      (__attribute__((address_space(3))) unsigned int*)l,
      16, 0, 0);
}

// ---------------- prep: transpose+cast all weights ----------------
// z=0: W0 (16x512 -> [512][32]);  z=1..3: W1..W3 (512x512 -> [512][512])
// z=4..11: U0; 12..19: U1; 20..27: U2 (512x512 -> [512][512])
// z=28..35: U3 (512x64 -> [128][512], rows 64..127 zero; fused uses rows 0..63)
__global__ void prep_k(const float* W0, f16* Wt0, const float* W1, f16* Wt1,
                       const float* W2, f16* Wt2, const float* W3, f16* Wt3,
                       const float* U0, f16* U0t, const float* U1, f16* U1t,
                       const float* U2, f16* U2t, const float* U3, f16* U3t) {
  int z = blockIdx.z;
  const float* src; f16* dst; int Kin, Nin, Kpad, Npad;
  if (z == 0)      { src = W0; dst = Wt0; Kin = 16;  Nin = 512; Kpad = 32;  Npad = 512; }
  else if (z == 1) { src = W1; dst = Wt1; Kin = 512; Nin = 512; Kpad = 512; Npad = 512; }
  else if (z == 2) { src = W2; dst = Wt2; Kin = 512; Nin = 512; Kpad = 512; Npad = 512; }
  else if (z == 3) { src = W3; dst = Wt3; Kin = 512; Nin = 512; Kpad = 512; Npad = 512; }
  else if (z < 12) { int d = z - 4;  src = U0 + (long)d * 262144; dst = U0t + (long)d * 262144; Kin = 512; Nin = 512; Kpad = 512; Npad = 512; }
  else if (z < 20) { int d = z - 12; src = U1 + (long)d * 262144; dst = U1t + (long)d * 262144; Kin = 512; Nin = 512; Kpad = 512; Npad = 512; }
  else if (z < 28) { int d = z - 20; src = U2 + (long)d * 262144; dst = U2t + (long)d * 262144; Kin = 512; Nin = 512; Kpad = 512; Npad = 512; }
  else             { int d = z - 28; src = U3 + (long)d * 32768;  dst = U3t + (long)d * 65536;  Kin = 512; Nin = 64;  Kpad = 512; Npad = 128; }

  __shared__ float tile[32][33];
  int k0 = blockIdx.y * 32, n0 = blockIdx.x * 32;
  int tx = threadIdx.x, ty = threadIdx.y;  // 32 x 8
  #pragma unroll
  for (int i = 0; i < 32; i += 8) {
    int k = k0 + ty + i, n = n0 + tx;
    tile[ty + i][tx] = (k < Kin && n < Nin) ? src[(long)k * Nin + n] : 0.f;
  }
  __syncthreads();
  #pragma unroll
  for (int i = 0; i < 32; i += 8) {
    int n = n0 + ty + i, k = k0 + tx;
    if (n < Npad && k < Kpad) dst[(long)n * Kpad + k] = (f16)tile[tx][ty + i];
  }
}

// ---------------- bucketing (atomics-free, deterministic) ----------------
// Domain ranges PADDED to multiples of 32; pad slots duplicate the domain's
// last row with bit31 set (skipped at final store). bases[0..8] padded cumsum.
#define NT_BUCKET 1024
#define RPT 16

__global__ __launch_bounds__(NT_BUCKET) void bucket_k(const int* __restrict__ y,
                                                      int* __restrict__ bases_out,
                                                      int* __restrict__ perm) {
  __shared__ int hist[ND_][NT_BUCKET];   // 32 KB; thread t owns column t
  __shared__ int totals[ND_];
  __shared__ int bases[ND_ + 1];
  __shared__ int realc[ND_];
  int t = threadIdx.x;
  int base = t * RPT;

  #pragma unroll
  for (int d = 0; d < ND_; d++) hist[d][t] = 0;
  int yv[RPT];
  #pragma unroll
  for (int i = 0; i < RPT; i++) {
    yv[i] = y[base + i];
    hist[yv[i]][t]++;
  }
  __syncthreads();

  int wave = t >> 6, lane = t & 63;
  if (wave < ND_) {
    int d = wave;
    int carry = 0;
    for (int c = 0; c < NT_BUCKET; c += 64) {
      int v = hist[d][c + lane];
      int s = v;
      #pragma unroll
      for (int off = 1; off < 64; off <<= 1) {
        int u = __shfl_up(s, off, 64);
        if (lane >= off) s += u;
      }
      hist[d][c + lane] = carry + s - v;   // exclusive prefix
      carry += __shfl(s, 63, 64);
    }
    if (lane == 0) totals[d] = carry;
  }
  __syncthreads();

  if (t == 0) {
    int s = 0;
    #pragma unroll
    for (int d = 0; d < ND_; d++) {
      bases[d] = s; bases_out[d] = s; realc[d] = totals[d];
      s += (totals[d] + 31) & ~31;
    }
    bases[ND_] = s; bases_out[ND_] = s;
  }
  __syncthreads();

  #pragma unroll
  for (int i = 0; i < RPT; i++) {
    int d = yv[i];
    int pos = bases[d] + hist[d][t];
    hist[d][t]++;
    perm[pos] = base + i;
  }
  __syncthreads();

  if (t < 256) {                            // fill pad slots
    int d = t >> 5, i = t & 31;
    int rc = realc[d];
    int padded = (rc + 31) & ~31;
    if (rc > 0 && i < padded - rc)
      perm[bases[d] + rc + i] = perm[bases[d] + rc - 1] | 0x80000000;
  }
}

// ---------------- fused MLP layer ----------------
// act: [32 rows][512 cols] f16 in LDS, XOR-swizzled (byte ^= (row&7)<<4).
// C = relu(A @ W + b) computed via SWAPPED mfma(bf, af) => lane holds one act-row
// (lane&15) and 4 contiguous output cols ((lane>>4)*4+j) per fragment -> 8B ds_write.
// W streamed global->LDS per K-step (NL x 32 f16, linear), single-buffered.
template<int KL, int NL, bool RELU, bool FINAL>
__device__ __forceinline__ void do_layer(
    const f16* __restrict__ W, const float* __restrict__ bias,
    f16* __restrict__ act, f16* __restrict__ wls,
    const int* __restrict__ rowinfo, float* __restrict__ out, int t) {
  const int lane = t & 63, wid = t >> 6;
  const int lr = lane & 15, lg = lane >> 4;
  constexpr int MF = FINAL ? 1 : 2;        // 16-row m-fragments per wave
  constexpr int NF = FINAL ? 2 : 8;        // 16-col n-fragments per wave
  constexpr int ROUNDS = NL / 64;          // 64-row staging slabs per K-step
  const int m_off = FINAL ? ((wid >> 1) * 16) : 0;
  const int wn = FINAL ? ((wid & 1) * 32) : (wid * 128);

  const f16* wptr = W + (long)(t >> 2) * KL + ((t & 3) << 3);
  f16* wdst = wls + wid * 512;
  char* actb = (char*)act;

  f32x4 acc[MF][NF];
  #pragma unroll
  for (int m = 0; m < MF; m++)
    #pragma unroll
    for (int n = 0; n < NF; n++) acc[m][n] = f32x4{0.f, 0.f, 0.f, 0.f};

  for (int kk = 0; kk < KL; kk += 32) {
    __syncthreads();                       // wls free (prev step's reads retired)
    #pragma unroll
    for (int rr = 0; rr < ROUNDS; rr++)
      gload16(wptr + (long)rr * 64 * KL + kk, wdst + rr * 2048);
    __syncthreads();                       // staged tile visible (vmcnt drained)

    f16x8 af[MF], bf[NF];
    #pragma unroll
    for (int m = 0; m < MF; m++) {
      int r = m_off + m * 16 + lr;
      int byte = r * 1024 + (((kk + lg * 8) * 2) ^ ((r & 7) << 4));
      af[m] = *(const f16x8*)(actb + byte);
    }
    #pragma unroll
    for (int n = 0; n < NF; n++)
      bf[n] = *(const f16x8*)&wls[(wn + n * 16 + lr) * 32 + lg * 8];
    #pragma unroll
    for (int m = 0; m < MF; m++)
      #pragma unroll
      for (int n = 0; n < NF; n++)
        acc[m][n] = __builtin_amdgcn_mfma_f32_16x16x32_f16(bf[n], af[m], acc[m][n], 0, 0, 0);
  }

  __syncthreads();                         // all act reads done before overwrite

  if (FINAL) {
    int r = m_off + lr;
    int info = rowinfo[r];
    if (info >= 0) {
      #pragma unroll
      for (int n = 0; n < NF; n++) {
        int cn0 = wn + n * 16 + lg * 4;
        f32x4 bb = *(const f32x4*)(bias + cn0);
        f32x4 v;
        #pragma unroll
        for (int j = 0; j < 4; j++) v[j] = acc[0][n][j] + bb[j];
        *(f32x4*)(out + (long)info * STY_ + cn0) = v;
      }
    }
  } else {
    #pragma unroll
    for (int m = 0; m < MF; m++) {
      int r = m_off + m * 16 + lr;
      #pragma unroll
      for (int n = 0; n < NF; n++) {
        int cn0 = wn + n * 16 + lg * 4;
        f32x4 bb = *(const f32x4*)(bias + cn0);
        f16x4 h;
        #pragma unroll
        for (int j = 0; j < 4; j++) {
          float v = acc[m][n][j] + bb[j];
          if (RELU) v = fmaxf(v, 0.f);
          h[j] = (f16)v;
        }
        int byte = r * 1024 + ((cn0 * 2) ^ ((r & 7) << 4));
        *(f16x4*)(actb + byte) = h;
      }
    }
  }
  // next layer's first __syncthreads separates these writes from its act reads
}

// ---------------- fused network kernel ----------------
__global__ __launch_bounds__(256) void fused_k(
    const float* __restrict__ x,
    const f16* __restrict__ Wt0, const float* __restrict__ b0,
    const f16* __restrict__ Wt1, const float* __restrict__ b1,
    const f16* __restrict__ Wt2, const float* __restrict__ b2,
    const f16* __restrict__ Wt3, const float* __restrict__ b3,
    const f16* __restrict__ U0t, const float* __restrict__ c0,
    const f16* __restrict__ U1t, const float* __restrict__ c1,
    const f16* __restrict__ U2t, const float* __restrict__ c2,
    const f16* __restrict__ U3t, const float* __restrict__ c3,
    const int* __restrict__ bases, const int* __restrict__ perm,
    float* __restrict__ out) {
  __shared__ f16 act[ROWS * 512];          // 32 KB
  __shared__ f16 wls[512 * 32];            // 32 KB
  __shared__ int rowinfo[ROWS];

  int t = threadIdx.x;
  int slot0 = blockIdx.x * ROWS;
  if (slot0 >= bases[ND_]) return;

  int dom = 0;
  #pragma unroll
  for (int d = 1; d < ND_; d++) dom += (slot0 >= bases[d]);

  if (t < ROWS) rowinfo[t] = perm[slot0 + t];
  __syncthreads();

  // gather x (f32 [16]) into act rows, cols 16..31 zero, swizzled
  char* actb = (char*)act;
  #pragma unroll
  for (int i = 0; i < 4; i++) {
    int e = i * 256 + t;
    int r = e >> 5, c = e & 31;
    int orig = rowinfo[r] & 0x7fffffff;
    f16 v = (c < LAT_) ? (f16)x[orig * LAT_ + c] : (f16)0.f;
    int byte = r * 1024 + ((c * 2) ^ ((r & 7) << 4));
    *(f16*)(actb + byte) = v;
  }

  do_layer<32,  512, true,  false>(Wt0, b0, act, wls, rowinfo, out, t);
  do_layer<512, 512, true,  false>(Wt1, b1, act, wls, rowinfo, out, t);
  do_layer<512, 512, true,  false>(Wt2, b2, act, wls, rowinfo, out, t);
  do_layer<512, 512, true,  false>(Wt3, b3, act, wls, rowinfo, out, t);
  long wd = (long)dom * 262144;
  do_layer<512, 512, true,  false>(U0t + wd, c0 + dom * 512, act, wls, rowinfo, out, t);
  do_layer<512, 512, true,  false>(U1t + wd, c1 + dom * 512, act, wls, rowinfo, out, t);
  do_layer<512, 512, true,  false>(U2t + wd, c2 + dom * 512, act, wls, rowinfo, out, t);
  do_layer<512, 64,  false, true >(U3t + (long)dom * 65536, c3 + dom * 64, act, wls, rowinfo, out, t);
}

// ---------------- launch ----------------

extern "C" void kernel_launch(void* const* d_in, const int* in_sizes, int n_in,
                              void* d_out, int out_size, void* d_ws, size_t ws_size,
                              hipStream_t stream) {
  const float* x  = (const float*)d_in[0];
  const int*   y  = (const int*)  d_in[1];
  const float* W0 = (const float*)d_in[2];
  const float* b0 = (const float*)d_in[3];
  const float* W1 = (const float*)d_in[4];
  const float* b1 = (const float*)d_in[5];
  const float* W2 = (const float*)d_in[6];
  const float* b2 = (const float*)d_in[7];
  const float* W3 = (const float*)d_in[8];
  const float* b3 = (const float*)d_in[9];
  const float* U0 = (const float*)d_in[10];
  const float* c0 = (const float*)d_in[11];
  const float* U1 = (const float*)d_in[12];
  const float* c1 = (const float*)d_in[13];
  const float* U2 = (const float*)d_in[14];
  const float* c2 = (const float*)d_in[15];
  const float* U3 = (const float*)d_in[16];
  const float* c3 = (const float*)d_in[17];
  float* out = (float*)d_out;

  char* p = (char*)d_ws;
  auto alloc = [&](size_t bytes) -> char* {
    char* r = p; p += (bytes + 255) & ~(size_t)255; return r;
  };
  f16* Wt0 = (f16*)alloc((size_t)512 * 32 * 2);
  f16* Wt1 = (f16*)alloc((size_t)512 * 512 * 2);
  f16* Wt2 = (f16*)alloc((size_t)512 * 512 * 2);
  f16* Wt3 = (f16*)alloc((size_t)512 * 512 * 2);
  f16* U0t = (f16*)alloc((size_t)ND_ * 512 * 512 * 2);
  f16* U1t = (f16*)alloc((size_t)ND_ * 512 * 512 * 2);
  f16* U2t = (f16*)alloc((size_t)ND_ * 512 * 512 * 2);
  f16* U3t = (f16*)alloc((size_t)ND_ * 128 * 512 * 2);
  int* bases = (int*)alloc((ND_ + 1) * 4);
  int* perm  = (int*)alloc((size_t)(B_TOT + 256) * 4);

  prep_k<<<dim3(16, 16, 36), dim3(32, 8), 0, stream>>>(W0, Wt0, W1, Wt1, W2, Wt2, W3, Wt3,
                                                       U0, U0t, U1, U1t, U2, U2t, U3, U3t);
  bucket_k<<<1, NT_BUCKET, 0, stream>>>(y, bases, perm);
  fused_k<<<MAXBLK, 256, 0, stream>>>(x, Wt0, b0, Wt1, b1, Wt2, b2, Wt3, b3,
                                      U0t, c0, U1t, c1, U2t, c2, U3t, c3,
                                      bases, perm, out);
}

// Round 6
// 163.956 us; speedup vs baseline: 1.3534x; 1.3534x over previous
//
#include <hip/hip_runtime.h>

typedef _Float16 f16;
typedef _Float16 f16x4 __attribute__((ext_vector_type(4)));
typedef _Float16 f16x8 __attribute__((ext_vector_type(8)));
typedef float f32x4 __attribute__((ext_vector_type(4)));

#define B_TOT 16384
#define HID_  512
#define LAT_  16
#define STY_  64
#define ND_   8

#define ROWS 64            // rows per block, held in LDS through all 8 layers
#define NTHR 512           // 8 waves
#define NBLK 256           // B_TOT / ROWS, exactly 1 block/CU

// async global->LDS, 16B per lane; LDS dest is wave-uniform base (+lane*16 by HW)
__device__ __forceinline__ void gload16(const f16* g, f16* l) {
  __builtin_amdgcn_global_load_lds(
      (const __attribute__((address_space(1))) unsigned int*)g,
      (__attribute__((address_space(3))) unsigned int*)l,
      16, 0, 0);
}

// ---------------- prep: transpose+cast all weights ----------------
// z=0: W0 (16x512 -> [512][32]);  z=1..3: W1..W3 (512x512 -> [512][512])
// z=4..11: U0; 12..19: U1; 20..27: U2 (512x512 -> [512][512])
// z=28..35: U3 (512x64 -> [128][512]; fused uses rows 0..63)
__global__ void prep_k(const float* W0, f16* Wt0, const float* W1, f16* Wt1,
                       const float* W2, f16* Wt2, const float* W3, f16* Wt3,
                       const float* U0, f16* U0t, const float* U1, f16* U1t,
                       const float* U2, f16* U2t, const float* U3, f16* U3t) {
  int z = blockIdx.z;
  const float* src; f16* dst; int Kin, Nin, Kpad, Npad;
  if (z == 0)      { src = W0; dst = Wt0; Kin = 16;  Nin = 512; Kpad = 32;  Npad = 512; }
  else if (z == 1) { src = W1; dst = Wt1; Kin = 512; Nin = 512; Kpad = 512; Npad = 512; }
  else if (z == 2) { src = W2; dst = Wt2; Kin = 512; Nin = 512; Kpad = 512; Npad = 512; }
  else if (z == 3) { src = W3; dst = Wt3; Kin = 512; Nin = 512; Kpad = 512; Npad = 512; }
  else if (z < 12) { int d = z - 4;  src = U0 + (long)d * 262144; dst = U0t + (long)d * 262144; Kin = 512; Nin = 512; Kpad = 512; Npad = 512; }
  else if (z < 20) { int d = z - 12; src = U1 + (long)d * 262144; dst = U1t + (long)d * 262144; Kin = 512; Nin = 512; Kpad = 512; Npad = 512; }
  else if (z < 28) { int d = z - 20; src = U2 + (long)d * 262144; dst = U2t + (long)d * 262144; Kin = 512; Nin = 512; Kpad = 512; Npad = 512; }
  else             { int d = z - 28; src = U3 + (long)d * 32768;  dst = U3t + (long)d * 65536;  Kin = 512; Nin = 64;  Kpad = 512; Npad = 128; }

  __shared__ float tile[32][33];
  int k0 = blockIdx.y * 32, n0 = blockIdx.x * 32;
  int tx = threadIdx.x, ty = threadIdx.y;  // 32 x 8
  #pragma unroll
  for (int i = 0; i < 32; i += 8) {
    int k = k0 + ty + i, n = n0 + tx;
    tile[ty + i][tx] = (k < Kin && n < Nin) ? src[(long)k * Nin + n] : 0.f;
  }
  __syncthreads();
  #pragma unroll
  for (int i = 0; i < 32; i += 8) {
    int n = n0 + ty + i, k = k0 + tx;
    if (n < Npad && k < Kpad) dst[(long)n * Kpad + k] = (f16)tile[tx][ty + i];
  }
}

// ---------------- bucketing (atomics-free, deterministic, no padding) -------
#define NT_BUCKET 1024
#define RPT 16

__global__ __launch_bounds__(NT_BUCKET) void bucket_k(const int* __restrict__ y,
                                                      int* __restrict__ offsets,
                                                      int* __restrict__ perm) {
  __shared__ int hist[ND_][NT_BUCKET];
  __shared__ int totals[ND_];
  __shared__ int bases[ND_ + 1];
  int t = threadIdx.x;
  int base = t * RPT;

  #pragma unroll
  for (int d = 0; d < ND_; d++) hist[d][t] = 0;
  int yv[RPT];
  #pragma unroll
  for (int i = 0; i < RPT; i++) {
    yv[i] = y[base + i];
    hist[yv[i]][t]++;
  }
  __syncthreads();

  int wave = t >> 6, lane = t & 63;
  if (wave < ND_) {
    int d = wave;
    int carry = 0;
    for (int c = 0; c < NT_BUCKET; c += 64) {
      int v = hist[d][c + lane];
      int s = v;
      #pragma unroll
      for (int off = 1; off < 64; off <<= 1) {
        int u = __shfl_up(s, off, 64);
        if (lane >= off) s += u;
      }
      hist[d][c + lane] = carry + s - v;   // exclusive prefix
      carry += __shfl(s, 63, 64);
    }
    if (lane == 0) totals[d] = carry;
  }
  __syncthreads();

  if (t == 0) {
    int s = 0;
    #pragma unroll
    for (int d = 0; d < ND_; d++) { bases[d] = s; offsets[d] = s; s += totals[d]; }
    bases[ND_] = s; offsets[ND_] = s;
  }
  __syncthreads();

  #pragma unroll
  for (int i = 0; i < RPT; i++) {
    int d = yv[i];
    int pos = bases[d] + hist[d][t];
    hist[d][t]++;
    perm[pos] = base + i;
  }
}

// ---------------- fused layer ----------------
// act: [64 rows][512 cols] f16 in LDS, byte ^= ((row&7)<<4) swizzle.
// Swapped mfma(bf, af): lane holds act-row = lane&15(+16m), out-cols = wn+16n+lg*4+j.
// Weights [NL rows(out-cols)][KL] streamed global->LDS (linear), double-buffered.
// Epilogue writes act (or scatters f32 out if FINAL) for rows in [rlo,rhi).
template<int KL, int NL, bool RELU, bool FINAL>
__device__ __forceinline__ void do_layer(
    const f16* __restrict__ W, const float* __restrict__ bias,
    f16* __restrict__ act, f16* __restrict__ wls,  // wls = [2][16384] f16
    int rlo, int rhi,
    const int* __restrict__ perm, int slot0, float* __restrict__ out, int t) {
  const int lane = t & 63, wid = t >> 6;
  const int lr = lane & 15, lg = lane >> 4;
  constexpr int NSTEP = KL / 32;
  constexpr int MF = FINAL ? 2 : 4;
  constexpr int NF = FINAL ? 1 : 4;
  const int m0 = FINAL ? ((wid >> 2) * 32) : 0;
  const int wn = FINAL ? ((wid & 3) * 16) : (wid * 64);
  char* actb = (char*)act;

  // staging: chunk p covers (row p>>2, k-col (p&3)*8); p = i*512 + t (NL=512)
  const f16* wsrc = W + (long)(t >> 2) * KL + ((t & 3) << 3);
  const int wb = wid * 512;               // f16 offset of this wave's 1KB chunk

  f32x4 acc[MF][NF];
  #pragma unroll
  for (int m = 0; m < MF; m++)
    #pragma unroll
    for (int n = 0; n < NF; n++) acc[m][n] = f32x4{0.f, 0.f, 0.f, 0.f};

  #define STAGE_(buf, kk) do {                                              \
    if (!FINAL) {                                                           \
      _Pragma("unroll")                                                     \
      for (int i = 0; i < 4; i++)                                           \
        gload16(wsrc + (long)i * 128 * KL + (kk),                           \
                wls + (buf) * 16384 + i * 4096 + wb);                       \
    } else if (wid < 4) {                                                   \
      gload16(wsrc + (kk), wls + (buf) * 16384 + wb);                       \
    }                                                                       \
  } while (0)

  #define COMPUTE_(buf, kk) do {                                            \
    f16x8 af[MF], bf[NF];                                                   \
    _Pragma("unroll")                                                       \
    for (int m = 0; m < MF; m++) {                                          \
      int r = m0 + m * 16 + lr;                                             \
      af[m] = *(const f16x8*)(actb + r * 1024 +                             \
              ((((kk) + lg * 8) * 2) ^ ((r & 7) << 4)));                    \
    }                                                                       \
    _Pragma("unroll")                                                       \
    for (int n = 0; n < NF; n++)                                            \
      bf[n] = *(const f16x8*)&wls[(buf) * 16384 + (wn + n * 16 + lr) * 32 + lg * 8]; \
    _Pragma("unroll")                                                       \
    for (int m = 0; m < MF; m++)                                            \
      _Pragma("unroll")                                                     \
      for (int n = 0; n < NF; n++)                                          \
        acc[m][n] = __builtin_amdgcn_mfma_f32_16x16x32_f16(bf[n], af[m], acc[m][n], 0, 0, 0); \
  } while (0)

  STAGE_(0, 0);
  __syncthreads();                        // drains vmcnt; orders prior act writes
  int cur = 0;
  #pragma unroll 1
  for (int ts = 0; ts < NSTEP - 1; ++ts) {
    STAGE_(cur ^ 1, (ts + 1) * 32);       // prefetch next tile (in flight)
    COMPUTE_(cur, ts * 32);
    asm volatile("s_waitcnt vmcnt(0)" ::: "memory");
    __builtin_amdgcn_s_barrier();
    cur ^= 1;
  }
  COMPUTE_(cur, (NSTEP - 1) * 32);
  __syncthreads();                        // all act reads done before overwrite
  #undef STAGE_
  #undef COMPUTE_

  if (FINAL) {
    #pragma unroll
    for (int m = 0; m < MF; m++) {
      int r = m0 + m * 16 + lr;
      if (r >= rlo && r < rhi) {
        int orig = perm[slot0 + r];
        int cn0 = wn + lg * 4;
        f32x4 bb = *(const f32x4*)(bias + cn0);
        f32x4 v;
        #pragma unroll
        for (int j = 0; j < 4; j++) v[j] = acc[m][0][j] + bb[j];
        *(f32x4*)(out + (long)orig * STY_ + cn0) = v;
      }
    }
  } else {
    #pragma unroll
    for (int m = 0; m < MF; m++) {
      int r = m * 16 + lr;
      bool ok = (r >= rlo) && (r < rhi);
      #pragma unroll
      for (int n = 0; n < NF; n++) {
        int cn0 = wn + n * 16 + lg * 4;
        f32x4 bb = *(const f32x4*)(bias + cn0);
        f16x4 h;
        #pragma unroll
        for (int j = 0; j < 4; j++) {
          float v = acc[m][n][j] + bb[j];
          if (RELU) v = fmaxf(v, 0.f);
          h[j] = (f16)v;
        }
        if (ok)
          *(f16x4*)(actb + r * 1024 + ((cn0 * 2) ^ ((r & 7) << 4))) = h;
      }
    }
  }
}

// ---------------- fused network kernel ----------------
__global__ __launch_bounds__(NTHR) void fused_k(
    const float* __restrict__ x,
    const f16* __restrict__ Wt0, const float* __restrict__ b0,
    const f16* __restrict__ Wt1, const float* __restrict__ b1,
    const f16* __restrict__ Wt2, const float* __restrict__ b2,
    const f16* __restrict__ Wt3, const float* __restrict__ b3,
    const f16* __restrict__ U0t, const float* __restrict__ c0,
    const f16* __restrict__ U1t, const float* __restrict__ c1,
    const f16* __restrict__ U2t, const float* __restrict__ c2,
    const f16* __restrict__ U3t, const float* __restrict__ c3,
    const int* __restrict__ offs, const int* __restrict__ perm,
    float* __restrict__ out) {
  __shared__ f16 act[ROWS * 512];          // 64 KB, swizzled
  __shared__ f16 wls[2][512 * 32];         // 64 KB, linear

  int t = threadIdx.x;
  // XCD-chunked bijective swizzle (nwg=256, 8 XCDs): XCD i gets 32 consecutive tiles
  int wg = (blockIdx.x & 7) * (NBLK / 8) + (blockIdx.x >> 3);
  int slot0 = wg * ROWS;

  // gather x rows via perm into act (cols 16..31 zero), swizzled writes
  char* actb = (char*)act;
  #pragma unroll
  for (int i = 0; i < 4; i++) {
    int e = i * NTHR + t;                  // 0..2047
    int r = e >> 5, c = e & 31;
    int orig = perm[slot0 + r];
    f16 v = (c < LAT_) ? (f16)x[orig * LAT_ + c] : (f16)0.f;
    *(f16*)(actb + r * 1024 + ((c * 2) ^ ((r & 7) << 4))) = v;
  }
  // (layer prologue __syncthreads orders these writes before first af read)

  // domain span of this block's 64 consecutive slots
  int d0 = 0, d1 = 0;
  #pragma unroll
  for (int d = 1; d < ND_; d++) {
    d0 += (slot0 >= offs[d]);
    d1 += (slot0 + ROWS - 1 >= offs[d]);
  }

  // trunk (shared weights, full row range)
  do_layer<32,  512, true, false>(Wt0, b0, act, &wls[0][0], 0, ROWS, perm, slot0, out, t);
  do_layer<512, 512, true, false>(Wt1, b1, act, &wls[0][0], 0, ROWS, perm, slot0, out, t);
  do_layer<512, 512, true, false>(Wt2, b2, act, &wls[0][0], 0, ROWS, perm, slot0, out, t);
  do_layer<512, 512, true, false>(Wt3, b3, act, &wls[0][0], 0, ROWS, perm, slot0, out, t);

  // experts: boundary blocks (d0<d1) run each layer once per domain, row-masked
  #pragma unroll 1
  for (int d = d0; d <= d1; d++) {
    int rlo = (d == d0) ? 0 : (offs[d] - slot0);
    int rhi = (d == d1) ? ROWS : (offs[d + 1] - slot0);
    do_layer<512, 512, true, false>(U0t + (long)d * 262144, c0 + d * 512,
                                    act, &wls[0][0], rlo, rhi, perm, slot0, out, t);
  }
  #pragma unroll 1
  for (int d = d0; d <= d1; d++) {
    int rlo = (d == d0) ? 0 : (offs[d] - slot0);
    int rhi = (d == d1) ? ROWS : (offs[d + 1] - slot0);
    do_layer<512, 512, true, false>(U1t + (long)d * 262144, c1 + d * 512,
                                    act, &wls[0][0], rlo, rhi, perm, slot0, out, t);
  }
  #pragma unroll 1
  for (int d = d0; d <= d1; d++) {
    int rlo = (d == d0) ? 0 : (offs[d] - slot0);
    int rhi = (d == d1) ? ROWS : (offs[d + 1] - slot0);
    do_layer<512, 512, true, false>(U2t + (long)d * 262144, c2 + d * 512,
                                    act, &wls[0][0], rlo, rhi, perm, slot0, out, t);
  }
  #pragma unroll 1
  for (int d = d0; d <= d1; d++) {
    int rlo = (d == d0) ? 0 : (offs[d] - slot0);
    int rhi = (d == d1) ? ROWS : (offs[d + 1] - slot0);
    do_layer<512, 64, false, true>(U3t + (long)d * 65536, c3 + d * 64,
                                   act, &wls[0][0], rlo, rhi, perm, slot0, out, t);
  }
}

// ---------------- launch ----------------

extern "C" void kernel_launch(void* const* d_in, const int* in_sizes, int n_in,
                              void* d_out, int out_size, void* d_ws, size_t ws_size,
                              hipStream_t stream) {
  const float* x  = (const float*)d_in[0];
  const int*   y  = (const int*)  d_in[1];
  const float* W0 = (const float*)d_in[2];
  const float* b0 = (const float*)d_in[3];
  const float* W1 = (const float*)d_in[4];
  const float* b1 = (const float*)d_in[5];
  const float* W2 = (const float*)d_in[6];
  const float* b2 = (const float*)d_in[7];
  const float* W3 = (const float*)d_in[8];
  const float* b3 = (const float*)d_in[9];
  const float* U0 = (const float*)d_in[10];
  const float* c0 = (const float*)d_in[11];
  const float* U1 = (const float*)d_in[12];
  const float* c1 = (const float*)d_in[13];
  const float* U2 = (const float*)d_in[14];
  const float* c2 = (const float*)d_in[15];
  const float* U3 = (const float*)d_in[16];
  const float* c3 = (const float*)d_in[17];
  float* out = (float*)d_out;

  char* p = (char*)d_ws;
  auto alloc = [&](size_t bytes) -> char* {
    char* r = p; p += (bytes + 255) & ~(size_t)255; return r;
  };
  f16* Wt0 = (f16*)alloc((size_t)512 * 32 * 2);
  f16* Wt1 = (f16*)alloc((size_t)512 * 512 * 2);
  f16* Wt2 = (f16*)alloc((size_t)512 * 512 * 2);
  f16* Wt3 = (f16*)alloc((size_t)512 * 512 * 2);
  f16* U0t = (f16*)alloc((size_t)ND_ * 512 * 512 * 2);
  f16* U1t = (f16*)alloc((size_t)ND_ * 512 * 512 * 2);
  f16* U2t = (f16*)alloc((size_t)ND_ * 512 * 512 * 2);
  f16* U3t = (f16*)alloc((size_t)ND_ * 128 * 512 * 2);
  int* offsets = (int*)alloc((ND_ + 1) * 4);
  int* perm    = (int*)alloc((size_t)B_TOT * 4);

  prep_k<<<dim3(16, 16, 36), dim3(32, 8), 0, stream>>>(W0, Wt0, W1, Wt1, W2, Wt2, W3, Wt3,
                                                       U0, U0t, U1, U1t, U2, U2t, U3, U3t);
  bucket_k<<<1, NT_BUCKET, 0, stream>>>(y, offsets, perm);
  fused_k<<<NBLK, NTHR, 0, stream>>>(x, Wt0, b0, Wt1, b1, Wt2, b2, Wt3, b3,
                                     U0t, c0, U1t, c1, U2t, c2, U3t, c3,
                                     offsets, perm, out);
}

// Round 7
// 120.004 us; speedup vs baseline: 1.8491x; 1.3663x over previous
//
#include <hip/hip_runtime.h>

typedef _Float16 f16;
typedef _Float16 f16x4 __attribute__((ext_vector_type(4)));
typedef _Float16 f16x8 __attribute__((ext_vector_type(8)));
typedef float f32x4 __attribute__((ext_vector_type(4)));

#define B_TOT 16384
#define HID_  512
#define LAT_  16
#define STY_  64
#define ND_   8

#define ROWS 64            // rows per block, held in LDS through all 8 layers
#define NTHR 512           // 8 waves
#define NBLK 256           // B_TOT / ROWS, exactly 1 block/CU

// ---------------- prep: transpose+cast all weights into k-tiled fragment layout -
// dst elem (out-col n, k) -> dst[((k>>5)*NR + n)*32 + (k&31)]   (f16)
// z=0: W0 (16x512, Kpad=32, NR=512); z=1..3: W1..W3 (512x512, NR=512)
// z=4..11: U0; 12..19: U1; 20..27: U2 (512x512, NR=512)
// z=28..35: U3 (512x64, NR=64)
__global__ void prep_k(const float* W0, f16* Wt0, const float* W1, f16* Wt1,
                       const float* W2, f16* Wt2, const float* W3, f16* Wt3,
                       const float* U0, f16* U0t, const float* U1, f16* U1t,
                       const float* U2, f16* U2t, const float* U3, f16* U3t) {
  int z = blockIdx.z;
  const float* src; f16* dst; int Kin, Nin, Kpad, NR;
  if (z == 0)      { src = W0; dst = Wt0; Kin = 16;  Nin = 512; Kpad = 32;  NR = 512; }
  else if (z == 1) { src = W1; dst = Wt1; Kin = 512; Nin = 512; Kpad = 512; NR = 512; }
  else if (z == 2) { src = W2; dst = Wt2; Kin = 512; Nin = 512; Kpad = 512; NR = 512; }
  else if (z == 3) { src = W3; dst = Wt3; Kin = 512; Nin = 512; Kpad = 512; NR = 512; }
  else if (z < 12) { int d = z - 4;  src = U0 + (long)d * 262144; dst = U0t + (long)d * 262144; Kin = 512; Nin = 512; Kpad = 512; NR = 512; }
  else if (z < 20) { int d = z - 12; src = U1 + (long)d * 262144; dst = U1t + (long)d * 262144; Kin = 512; Nin = 512; Kpad = 512; NR = 512; }
  else if (z < 28) { int d = z - 20; src = U2 + (long)d * 262144; dst = U2t + (long)d * 262144; Kin = 512; Nin = 512; Kpad = 512; NR = 512; }
  else             { int d = z - 28; src = U3 + (long)d * 32768;  dst = U3t + (long)d * 32768;  Kin = 512; Nin = 64;  Kpad = 512; NR = 64; }

  __shared__ float tile[32][33];
  int k0 = blockIdx.y * 32, n0 = blockIdx.x * 32;
  int tx = threadIdx.x, ty = threadIdx.y;  // 32 x 8
  #pragma unroll
  for (int i = 0; i < 32; i += 8) {
    int k = k0 + ty + i, n = n0 + tx;
    tile[ty + i][tx] = (k < Kin && n < Nin) ? src[(long)k * Nin + n] : 0.f;
  }
  __syncthreads();
  #pragma unroll
  for (int i = 0; i < 32; i += 8) {
    int n = n0 + ty + i, k = k0 + tx;
    if (n < NR && k < Kpad)
      dst[(long)(((k >> 5) * NR + n) << 5) | (k & 31)] = (f16)tile[tx][ty + i];
  }
}

// ---------------- bucketing (atomics-free, deterministic) ----------------
#define NT_BUCKET 1024
#define RPT 16

__global__ __launch_bounds__(NT_BUCKET) void bucket_k(const int* __restrict__ y,
                                                      int* __restrict__ offsets,
                                                      int* __restrict__ perm) {
  __shared__ int hist[ND_][NT_BUCKET];
  __shared__ int totals[ND_];
  __shared__ int bases[ND_ + 1];
  int t = threadIdx.x;
  int base = t * RPT;

  #pragma unroll
  for (int d = 0; d < ND_; d++) hist[d][t] = 0;
  int yv[RPT];
  #pragma unroll
  for (int i = 0; i < RPT; i++) {
    yv[i] = y[base + i];
    hist[yv[i]][t]++;
  }
  __syncthreads();

  int wave = t >> 6, lane = t & 63;
  if (wave < ND_) {
    int d = wave;
    int carry = 0;
    for (int c = 0; c < NT_BUCKET; c += 64) {
      int v = hist[d][c + lane];
      int s = v;
      #pragma unroll
      for (int off = 1; off < 64; off <<= 1) {
        int u = __shfl_up(s, off, 64);
        if (lane >= off) s += u;
      }
      hist[d][c + lane] = carry + s - v;   // exclusive prefix
      carry += __shfl(s, 63, 64);
    }
    if (lane == 0) totals[d] = carry;
  }
  __syncthreads();

  if (t == 0) {
    int s = 0;
    #pragma unroll
    for (int d = 0; d < ND_; d++) { bases[d] = s; offsets[d] = s; s += totals[d]; }
    bases[ND_] = s; offsets[ND_] = s;
  }
  __syncthreads();

  #pragma unroll
  for (int i = 0; i < RPT; i++) {
    int d = yv[i];
    int pos = bases[d] + hist[d][t];
    hist[d][t]++;
    perm[pos] = base + i;
  }
}

// ---------------- fused layer ----------------
// act: [64 rows][512 cols] f16 in LDS, byte ^= ((row&7)<<4) swizzle (2-way, free).
// Weights in k-tiled layout [KT][NR][32]; bf fragments loaded global->VGPR directly
// (lane reads 16B at ((wn+n*16+lr)*32 + lg*8); wave covers a contiguous 1KB span).
// Swapped mfma(bf, af): lane holds act-row lane&15, out-cols (lane>>4)*4+j.
// NO barriers inside the K-loop; 2 per layer.
template<int KT, bool FINAL>
__device__ __forceinline__ void do_layer(
    const f16* __restrict__ Wk, const float* __restrict__ bias,
    f16* __restrict__ act, int rlo, int rhi,
    const int* __restrict__ perm, int slot0, float* __restrict__ out, int t) {
  const int lane = t & 63, wid = t >> 6;
  const int lr = lane & 15, lg = lane >> 4;
  char* actb = (char*)act;

  __syncthreads();                       // previous layer's act writes visible

  if (!FINAL) {
    const int wn = wid * 64;
    const f16* wp[4];
    #pragma unroll
    for (int n = 0; n < 4; n++)
      wp[n] = Wk + ((wn + n * 16 + lr) * 32 + lg * 8);

    f32x4 acc[4][4];
    #pragma unroll
    for (int m = 0; m < 4; m++)
      #pragma unroll
      for (int n = 0; n < 4; n++) acc[m][n] = f32x4{0.f, 0.f, 0.f, 0.f};

    f16x8 ba[4], bb[4];
    #pragma unroll
    for (int n = 0; n < 4; n++) ba[n] = *(const f16x8*)(wp[n]);

    #define STEP_(kt, BC, BN_, PF) do {                                       \
      if (PF) {                                                               \
        _Pragma("unroll")                                                     \
        for (int n = 0; n < 4; n++)                                           \
          BN_[n] = *(const f16x8*)(wp[n] + ((kt) + 1) * 16384);               \
      }                                                                       \
      f16x8 af[4];                                                            \
      _Pragma("unroll")                                                       \
      for (int m = 0; m < 4; m++) {                                           \
        int r = m * 16 + lr;                                                  \
        af[m] = *(const f16x8*)(actb + r * 1024 +                             \
                ((((kt) * 32 + lg * 8) * 2) ^ ((r & 7) << 4)));               \
      }                                                                       \
      _Pragma("unroll")                                                       \
      for (int m = 0; m < 4; m++)                                             \
        _Pragma("unroll")                                                     \
        for (int n = 0; n < 4; n++)                                           \
          acc[m][n] = __builtin_amdgcn_mfma_f32_16x16x32_f16(BC[n], af[m], acc[m][n], 0, 0, 0); \
    } while (0)

    if constexpr (KT == 1) {
      STEP_(0, ba, bb, false);
    } else {
      #pragma unroll 2
      for (int kt2 = 0; kt2 < KT - 2; kt2 += 2) {
        STEP_(kt2, ba, bb, true);
        STEP_(kt2 + 1, bb, ba, true);
      }
      STEP_(KT - 2, ba, bb, true);
      STEP_(KT - 1, bb, ba, false);
    }
    #undef STEP_

    __syncthreads();                     // all af reads done before overwrite

    #pragma unroll
    for (int m = 0; m < 4; m++) {
      int r = m * 16 + lr;
      bool ok = (r >= rlo) && (r < rhi);
      #pragma unroll
      for (int n = 0; n < 4; n++) {
        int cn0 = wn + n * 16 + lg * 4;
        f32x4 bb2 = *(const f32x4*)(bias + cn0);
        f16x4 h;
        #pragma unroll
        for (int j = 0; j < 4; j++)
          h[j] = (f16)fmaxf(acc[m][n][j] + bb2[j], 0.f);
        if (ok)
          *(f16x4*)(actb + r * 1024 + ((cn0 * 2) ^ ((r & 7) << 4))) = h;
      }
    }
  } else {
    // final 512->64: wave covers rows (wid>>2)*32+{0,16}+lr, cols (wid&3)*16+lg*4
    const int m0 = (wid >> 2) * 32;
    const int wn = (wid & 3) * 16;
    const f16* wp0 = Wk + ((wn + lr) * 32 + lg * 8);
    f32x4 a0 = f32x4{0.f, 0.f, 0.f, 0.f}, a1 = a0;
    #pragma unroll 4
    for (int kt = 0; kt < 16; kt++) {
      f16x8 bf = *(const f16x8*)(wp0 + kt * 2048);   // [kt][64][32]
      int r0 = m0 + lr, r1 = m0 + 16 + lr;
      f16x8 af0 = *(const f16x8*)(actb + r0 * 1024 +
                   (((kt * 32 + lg * 8) * 2) ^ ((r0 & 7) << 4)));
      f16x8 af1 = *(const f16x8*)(actb + r1 * 1024 +
                   (((kt * 32 + lg * 8) * 2) ^ ((r1 & 7) << 4)));
      a0 = __builtin_amdgcn_mfma_f32_16x16x32_f16(bf, af0, a0, 0, 0, 0);
      a1 = __builtin_amdgcn_mfma_f32_16x16x32_f16(bf, af1, a1, 0, 0, 0);
    }
    int cn0 = wn + lg * 4;
    f32x4 bb2 = *(const f32x4*)(bias + cn0);
    #pragma unroll
    for (int m = 0; m < 2; m++) {
      int r = m0 + m * 16 + lr;
      if (r >= rlo && r < rhi) {
        int orig = perm[slot0 + r];
        f32x4 v;
        #pragma unroll
        for (int j = 0; j < 4; j++) v[j] = (m ? a1[j] : a0[j]) + bb2[j];
        *(f32x4*)(out + (long)orig * STY_ + cn0) = v;
      }
    }
  }
}

// ---------------- fused network kernel ----------------
__global__ __launch_bounds__(NTHR, 2) void fused_k(
    const float* __restrict__ x,
    const f16* __restrict__ Wt0, const float* __restrict__ b0,
    const f16* __restrict__ Wt1, const float* __restrict__ b1,
    const f16* __restrict__ Wt2, const float* __restrict__ b2,
    const f16* __restrict__ Wt3, const float* __restrict__ b3,
    const f16* __restrict__ U0t, const float* __restrict__ c0,
    const f16* __restrict__ U1t, const float* __restrict__ c1,
    const f16* __restrict__ U2t, const float* __restrict__ c2,
    const f16* __restrict__ U3t, const float* __restrict__ c3,
    const int* __restrict__ offs, const int* __restrict__ perm,
    float* __restrict__ out) {
  __shared__ f16 act[ROWS * 512];          // 64 KB, swizzled

  int t = threadIdx.x;
  // XCD-chunked bijective swizzle (nwg=256, 8 XCDs)
  int wg = (blockIdx.x & 7) * (NBLK / 8) + (blockIdx.x >> 3);
  int slot0 = wg * ROWS;

  // gather x rows via perm into act (cols 16..31 zero), swizzled writes
  char* actb = (char*)act;
  #pragma unroll
  for (int i = 0; i < 4; i++) {
    int e = i * NTHR + t;                  // 0..2047
    int r = e >> 5, c = e & 31;
    int orig = perm[slot0 + r];
    f16 v = (c < LAT_) ? (f16)x[orig * LAT_ + c] : (f16)0.f;
    *(f16*)(actb + r * 1024 + ((c * 2) ^ ((r & 7) << 4))) = v;
  }
  // (do_layer's entry __syncthreads orders these before the first af read)

  // domain span of this block's 64 consecutive slots
  int d0 = 0, d1 = 0;
  #pragma unroll
  for (int d = 1; d < ND_; d++) {
    d0 += (slot0 >= offs[d]);
    d1 += (slot0 + ROWS - 1 >= offs[d]);
  }

  // trunk (shared weights, full row range)
  do_layer<1,  false>(Wt0, b0, act, 0, ROWS, perm, slot0, out, t);
  do_layer<16, false>(Wt1, b1, act, 0, ROWS, perm, slot0, out, t);
  do_layer<16, false>(Wt2, b2, act, 0, ROWS, perm, slot0, out, t);
  do_layer<16, false>(Wt3, b3, act, 0, ROWS, perm, slot0, out, t);

  // experts: boundary blocks (d0<d1) run each layer once per domain, row-masked
  #pragma unroll 1
  for (int d = d0; d <= d1; d++) {
    int rlo = (d == d0) ? 0 : (offs[d] - slot0);
    int rhi = (d == d1) ? ROWS : (offs[d + 1] - slot0);
    do_layer<16, false>(U0t + (long)d * 262144, c0 + d * 512,
                        act, rlo, rhi, perm, slot0, out, t);
  }
  #pragma unroll 1
  for (int d = d0; d <= d1; d++) {
    int rlo = (d == d0) ? 0 : (offs[d] - slot0);
    int rhi = (d == d1) ? ROWS : (offs[d + 1] - slot0);
    do_layer<16, false>(U1t + (long)d * 262144, c1 + d * 512,
                        act, rlo, rhi, perm, slot0, out, t);
  }
  #pragma unroll 1
  for (int d = d0; d <= d1; d++) {
    int rlo = (d == d0) ? 0 : (offs[d] - slot0);
    int rhi = (d == d1) ? ROWS : (offs[d + 1] - slot0);
    do_layer<16, false>(U2t + (long)d * 262144, c2 + d * 512,
                        act, rlo, rhi, perm, slot0, out, t);
  }
  #pragma unroll 1
  for (int d = d0; d <= d1; d++) {
    int rlo = (d == d0) ? 0 : (offs[d] - slot0);
    int rhi = (d == d1) ? ROWS : (offs[d + 1] - slot0);
    do_layer<16, true>(U3t + (long)d * 32768, c3 + d * 64,
                       act, rlo, rhi, perm, slot0, out, t);
  }
}

// ---------------- launch ----------------

extern "C" void kernel_launch(void* const* d_in, const int* in_sizes, int n_in,
                              void* d_out, int out_size, void* d_ws, size_t ws_size,
                              hipStream_t stream) {
  const float* x  = (const float*)d_in[0];
  const int*   y  = (const int*)  d_in[1];
  const float* W0 = (const float*)d_in[2];
  const float* b0 = (const float*)d_in[3];
  const float* W1 = (const float*)d_in[4];
  const float* b1 = (const float*)d_in[5];
  const float* W2 = (const float*)d_in[6];
  const float* b2 = (const float*)d_in[7];
  const float* W3 = (const float*)d_in[8];
  const float* b3 = (const float*)d_in[9];
  const float* U0 = (const float*)d_in[10];
  const float* c0 = (const float*)d_in[11];
  const float* U1 = (const float*)d_in[12];
  const float* c1 = (const float*)d_in[13];
  const float* U2 = (const float*)d_in[14];
  const float* c2 = (const float*)d_in[15];
  const float* U3 = (const float*)d_in[16];
  const float* c3 = (const float*)d_in[17];
  float* out = (float*)d_out;

  char* p = (char*)d_ws;
  auto alloc = [&](size_t bytes) -> char* {
    char* r = p; p += (bytes + 255) & ~(size_t)255; return r;
  };
  f16* Wt0 = (f16*)alloc((size_t)512 * 32 * 2);
  f16* Wt1 = (f16*)alloc((size_t)512 * 512 * 2);
  f16* Wt2 = (f16*)alloc((size_t)512 * 512 * 2);
  f16* Wt3 = (f16*)alloc((size_t)512 * 512 * 2);
  f16* U0t = (f16*)alloc((size_t)ND_ * 512 * 512 * 2);
  f16* U1t = (f16*)alloc((size_t)ND_ * 512 * 512 * 2);
  f16* U2t = (f16*)alloc((size_t)ND_ * 512 * 512 * 2);
  f16* U3t = (f16*)alloc((size_t)ND_ * 16 * 64 * 32 * 2);
  int* offsets = (int*)alloc((ND_ + 1) * 4);
  int* perm    = (int*)alloc((size_t)B_TOT * 4);

  prep_k<<<dim3(16, 16, 36), dim3(32, 8), 0, stream>>>(W0, Wt0, W1, Wt1, W2, Wt2, W3, Wt3,
                                                       U0, U0t, U1, U1t, U2, U2t, U3, U3t);
  bucket_k<<<1, NT_BUCKET, 0, stream>>>(y, offsets, perm);
  fused_k<<<NBLK, NTHR, 0, stream>>>(x, Wt0, b0, Wt1, b1, Wt2, b2, Wt3, b3,
                                     U0t, c0, U1t, c1, U2t, c2, U3t, c3,
                                     offsets, perm, out);
}